// Round 4
// baseline (555.053 us; speedup 1.0000x reference)
//
#include <hip/hip_runtime.h>

#define BB 32
#define TT 4096
#define DD 512
#define HH 8
#define HDD 64
#define SCALE_F 0.125f   // 64^-0.5 exact
#define NCH 64           // chunks per batch
#define TC 64            // rows per chunk

// ---------------- A: u[b,h,:] = SCALE * Wk_h^T (Wq_h . enc[b,-1,:]) ----------
__global__ __launch_bounds__(256) void k_qu(const float* __restrict__ enc,
                                            const float* __restrict__ Wq,
                                            const float* __restrict__ Wk,
                                            float* __restrict__ u) {
    __shared__ float x[DD];
    __shared__ float qh[HDD];
    int b = blockIdx.x >> 3, h = blockIdx.x & 7;
    int tid = threadIdx.x;
    const float* el = enc + ((size_t)b * TT + (TT - 1)) * DD;
    for (int i = tid; i < DD; i += 256) x[i] = el[i];
    __syncthreads();
    if (tid < HDD) {
        const float4* wr = (const float4*)(Wq + (size_t)(h * HDD + tid) * DD);
        float acc = 0.f;
#pragma unroll 4
        for (int d = 0; d < DD / 4; ++d) {
            float4 w = wr[d];
            acc += w.x * x[4 * d] + w.y * x[4 * d + 1] + w.z * x[4 * d + 2] + w.w * x[4 * d + 3];
        }
        qh[tid] = acc;
    }
    __syncthreads();
#pragma unroll
    for (int k = 0; k < 2; ++k) {
        int d = tid + 256 * k;
        float acc = 0.f;
#pragma unroll 8
        for (int j = 0; j < HDD; ++j)
            acc += qh[j] * Wk[(size_t)(h * HDD + j) * DD + d];
        u[(size_t)(b * HH + h) * DD + d] = acc * SCALE_F;
    }
}

// ---------------- B: fused scores->exp->weighted-sum, one enc pass -----------
// grid = B*NCH blocks of 256. Chunk = 64 t-rows.
// Outputs: wt[b,h,t] = exp(s), lsum[b,c,h] = sum_t exp(s),
//          partial[b,c,h,d] = sum_t exp(s)*enc[b,t,d]  (unnormalized)
__global__ __launch_bounds__(256) void k_flash(const float* __restrict__ enc,
                                               const float* __restrict__ u,
                                               float* __restrict__ wt,
                                               float* __restrict__ lsum,
                                               float* __restrict__ partial) {
    __shared__ float stile[HH][66];   // scores then exp(scores)
    __shared__ float mrg[HH * DD];    // 16 KiB phase-3 merge
    int b = blockIdx.x >> 6;
    int c = blockIdx.x & 63;
    int t0 = c * TC;
    int wave = threadIdx.x >> 6, lane = threadIdx.x & 63;
    int tid = threadIdx.x;

    // ---- phase 1: scores for 64 rows (R3-verified fold butterfly) ----
    const float* ub = u + (size_t)b * HH * DD;
    float4 uA[HH], uB[HH];
#pragma unroll
    for (int h = 0; h < HH; ++h) {
        uA[h] = *(const float4*)(ub + h * DD + 4 * lane);
        uB[h] = *(const float4*)(ub + h * DD + 256 + 4 * lane);
    }
    bool b3 = (lane & 8) != 0, b4 = (lane & 16) != 0, b5 = (lane & 32) != 0;
    int myh = ((lane >> 3) & 1) * 4 + ((lane >> 4) & 1) * 2 + ((lane >> 5) & 1);
    for (int tt = wave; tt < TC; tt += 4) {
        int t = t0 + tt;
        const float* row = enc + ((size_t)b * TT + t) * DD;
        float4 e0 = *(const float4*)(row + 4 * lane);
        float4 e1 = *(const float4*)(row + 256 + 4 * lane);
        float a[HH];
#pragma unroll
        for (int h = 0; h < HH; ++h)
            a[h] = uA[h].x * e0.x + uA[h].y * e0.y + uA[h].z * e0.z + uA[h].w * e0.w
                 + uB[h].x * e1.x + uB[h].y * e1.y + uB[h].z * e1.z + uB[h].w * e1.w;
        float s[4];
#pragma unroll
        for (int j = 0; j < 4; ++j) {
            float snd = b3 ? a[j] : a[j + 4];
            float kp  = b3 ? a[j + 4] : a[j];
            s[j] = kp + __shfl_xor(snd, 8, 64);
        }
        float p[2];
#pragma unroll
        for (int j = 0; j < 2; ++j) {
            float snd = b4 ? s[j] : s[j + 2];
            float kp  = b4 ? s[j + 2] : s[j];
            p[j] = kp + __shfl_xor(snd, 16, 64);
        }
        float snd = b5 ? p[0] : p[1];
        float q0 = (b5 ? p[1] : p[0]) + __shfl_xor(snd, 32, 64);
        q0 += __shfl_xor(q0, 1, 64);
        q0 += __shfl_xor(q0, 2, 64);
        q0 += __shfl_xor(q0, 4, 64);
        if ((lane & 7) == 0) stile[myh][tt] = q0;
    }
    __syncthreads();

    // ---- phase 2: exponentiate tile, emit wt, per-chunk l ----
#pragma unroll
    for (int k = 0; k < 2; ++k) {
        int idx = tid + 256 * k;
        int h = idx >> 6, tt = idx & 63;
        float w = __expf(stile[h][tt]);
        stile[h][tt] = w;
        wt[(size_t)(b * HH + h) * TT + t0 + tt] = w;
    }
    __syncthreads();
    if (tid < HH) {
        float s = 0.f;
#pragma unroll
        for (int t = 0; t < TC; ++t) s += stile[tid][t];
        lsum[(size_t)(b * NCH + c) * HH + tid] = s;
    }

    // ---- phase 3: weighted enc-sum (R3-verified k_wsum structure, TC=64) ----
    int grp = tid >> 7, gl = tid & 127;
    float4 acc[HH];
#pragma unroll
    for (int h = 0; h < HH; ++h) acc[h] = make_float4(0.f, 0.f, 0.f, 0.f);
#pragma unroll 4
    for (int i = 0; i < TC / 2; ++i) {
        int r = grp + 2 * i;
        float4 e = *(const float4*)(enc + ((size_t)b * TT + t0 + r) * DD + gl * 4);
        float w0 = stile[0][r], w1 = stile[1][r], w2 = stile[2][r], w3 = stile[3][r];
        float w4 = stile[4][r], w5 = stile[5][r], w6 = stile[6][r], w7 = stile[7][r];
        acc[0].x += w0 * e.x; acc[0].y += w0 * e.y; acc[0].z += w0 * e.z; acc[0].w += w0 * e.w;
        acc[1].x += w1 * e.x; acc[1].y += w1 * e.y; acc[1].z += w1 * e.z; acc[1].w += w1 * e.w;
        acc[2].x += w2 * e.x; acc[2].y += w2 * e.y; acc[2].z += w2 * e.z; acc[2].w += w2 * e.w;
        acc[3].x += w3 * e.x; acc[3].y += w3 * e.y; acc[3].z += w3 * e.z; acc[3].w += w3 * e.w;
        acc[4].x += w4 * e.x; acc[4].y += w4 * e.y; acc[4].z += w4 * e.z; acc[4].w += w4 * e.w;
        acc[5].x += w5 * e.x; acc[5].y += w5 * e.y; acc[5].z += w5 * e.z; acc[5].w += w5 * e.w;
        acc[6].x += w6 * e.x; acc[6].y += w6 * e.y; acc[6].z += w6 * e.z; acc[6].w += w6 * e.w;
        acc[7].x += w7 * e.x; acc[7].y += w7 * e.y; acc[7].z += w7 * e.z; acc[7].w += w7 * e.w;
    }
    if (grp == 1) {
#pragma unroll
        for (int h = 0; h < HH; ++h) *(float4*)(mrg + h * DD + gl * 4) = acc[h];
    }
    __syncthreads();
    if (grp == 0) {
        float* pp = partial + (size_t)(b * NCH + c) * HH * DD + gl * 4;
#pragma unroll
        for (int h = 0; h < HH; ++h) {
            float4 m = *(const float4*)(mrg + h * DD + gl * 4);
            float4 r = acc[h];
            r.x += m.x; r.y += m.y; r.z += m.z; r.w += m.w;
            *(float4*)(pp + h * DD) = r;
        }
    }
}

// ---------------- F: ctx[b,h,d] = (sum_c partial) / (sum_c lsum) -------------
__global__ __launch_bounds__(256) void k_pred(const float* __restrict__ partial,
                                              const float* __restrict__ lsum,
                                              float* __restrict__ ctx) {
    int idx = blockIdx.x * 256 + threadIdx.x;   // over B*H*D/4
    int b = idx >> 10, r4 = (idx & 1023) * 4;
    int h = r4 >> 9;
    float L = 0.f;
#pragma unroll 8
    for (int c = 0; c < NCH; ++c) L += lsum[(size_t)(b * NCH + c) * HH + h];
    const float* pp = partial + (size_t)b * NCH * HH * DD + r4;
    float4 acc = make_float4(0.f, 0.f, 0.f, 0.f);
#pragma unroll 8
    for (int c = 0; c < NCH; ++c) {
        float4 v = *(const float4*)(pp + (size_t)c * HH * DD);
        acc.x += v.x; acc.y += v.y; acc.z += v.z; acc.w += v.w;
    }
    float inv = 1.0f / L;
    acc.x *= inv; acc.y *= inv; acc.z *= inv; acc.w *= inv;
    *(float4*)(ctx + (size_t)b * HH * DD + r4) = acc;
}

// ---------------- D: out1[b,t] = (1/8) sum_h wt[b,h,t] / L[b,h] --------------
__global__ __launch_bounds__(256) void k_out1(const float* __restrict__ wt,
                                              const float* __restrict__ lsum,
                                              float* __restrict__ out1) {
    __shared__ float Linv[HH];
    int b = blockIdx.x, tid = threadIdx.x;
    if (tid < HH) {
        float s = 0.f;
#pragma unroll 8
        for (int c = 0; c < NCH; ++c) s += lsum[(size_t)(b * NCH + c) * HH + tid];
        Linv[tid] = 0.125f / s;
    }
    __syncthreads();
#pragma unroll
    for (int k = 0; k < TT / 256; ++k) {
        int t = tid + 256 * k;
        float s = 0.f;
#pragma unroll
        for (int h = 0; h < HH; ++h)
            s += wt[(size_t)(b * HH + h) * TT + t] * Linv[h];
        out1[(size_t)b * TT + t] = s;
    }
}

// ---------------- G: ctxv = blockdiag(Wv) ctx ; out0 = Wo ctxv ----------------
__global__ __launch_bounds__(256) void k_vo(const float* __restrict__ ctx,
                                            const float* __restrict__ Wv,
                                            const float* __restrict__ Wo,
                                            float* __restrict__ out0) {
    __shared__ float cx[HH * DD];
    __shared__ float cv[DD];
    int b = blockIdx.x, tid = threadIdx.x;
    for (int i = tid; i < HH * DD; i += 256) cx[i] = ctx[(size_t)b * HH * DD + i];
    __syncthreads();
#pragma unroll
    for (int k = 0; k < 2; ++k) {
        int i = tid + 256 * k;
        int h = i >> 6;
        const float4* wr = (const float4*)(Wv + (size_t)i * DD);
        const float* cc = cx + h * DD;
        float acc = 0.f;
#pragma unroll 4
        for (int d = 0; d < DD / 4; ++d) {
            float4 w = wr[d];
            acc += w.x * cc[4 * d] + w.y * cc[4 * d + 1] + w.z * cc[4 * d + 2] + w.w * cc[4 * d + 3];
        }
        cv[i] = acc;
    }
    __syncthreads();
#pragma unroll
    for (int k = 0; k < 2; ++k) {
        int o = tid + 256 * k;
        const float4* wr = (const float4*)(Wo + (size_t)o * DD);
        float acc = 0.f;
#pragma unroll 4
        for (int d = 0; d < DD / 4; ++d) {
            float4 w = wr[d];
            acc += w.x * cv[4 * d] + w.y * cv[4 * d + 1] + w.z * cv[4 * d + 2] + w.w * cv[4 * d + 3];
        }
        out0[(size_t)b * DD + o] = acc;
    }
}

extern "C" void kernel_launch(void* const* d_in, const int* in_sizes, int n_in,
                              void* d_out, int out_size, void* d_ws, size_t ws_size,
                              hipStream_t stream) {
    const float* enc = (const float*)d_in[0];
    const float* Wq  = (const float*)d_in[1];
    const float* Wk  = (const float*)d_in[2];
    const float* Wv  = (const float*)d_in[3];
    const float* Wo  = (const float*)d_in[4];

    float* ws = (float*)d_ws;
    float* u       = ws;                                    // B*H*D      = 131072
    float* wt      = u + (size_t)BB * HH * DD;              // B*H*T      = 1048576
    float* lsum    = wt + (size_t)BB * HH * TT;             // B*NCH*H    = 16384
    float* partial = lsum + (size_t)BB * NCH * HH;          // B*NCH*H*D  = 8388608
    float* ctx     = partial + (size_t)BB * NCH * HH * DD;  // B*H*D      = 131072
    // total ~9.7M floats (~39 MB)

    float* out0 = (float*)d_out;          // [B, D]
    float* out1 = out0 + BB * DD;         // [B, T]

    hipLaunchKernelGGL(k_qu,    dim3(BB * HH),  dim3(256), 0, stream, enc, Wq, Wk, u);
    hipLaunchKernelGGL(k_flash, dim3(BB * NCH), dim3(256), 0, stream, enc, u, wt, lsum, partial);
    hipLaunchKernelGGL(k_pred,  dim3(BB * HH * DD / 1024), dim3(256), 0, stream, partial, lsum, ctx);
    hipLaunchKernelGGL(k_out1,  dim3(BB),       dim3(256), 0, stream, wt, lsum, out1);
    hipLaunchKernelGGL(k_vo,    dim3(BB),       dim3(256), 0, stream, ctx, Wv, Wo, out0);
}

// Round 5
// 495.349 us; speedup vs baseline: 1.1205x; 1.1205x over previous
//
#include <hip/hip_runtime.h>

#define BB 32
#define TT 4096
#define DD 512
#define HH 8
#define HDD 64
#define SCALE_F 0.125f   // 64^-0.5 exact
#define NCHS 64          // score chunks (64 rows each)
#define CHUNKS 32        // wsum chunks
#define TC 128           // rows per wsum chunk

// ---------------- A: u[b,h,:] = SCALE * Wk_h^T (Wq_h . enc[b,-1,:]) ----------
__global__ __launch_bounds__(256) void k_qu(const float* __restrict__ enc,
                                            const float* __restrict__ Wq,
                                            const float* __restrict__ Wk,
                                            float* __restrict__ u) {
    __shared__ float x[DD];
    __shared__ float qh[HDD];
    int b = blockIdx.x >> 3, h = blockIdx.x & 7;
    int tid = threadIdx.x;
    const float* el = enc + ((size_t)b * TT + (TT - 1)) * DD;
    for (int i = tid; i < DD; i += 256) x[i] = el[i];
    __syncthreads();
    if (tid < HDD) {
        const float4* wr = (const float4*)(Wq + (size_t)(h * HDD + tid) * DD);
        float acc = 0.f;
#pragma unroll 4
        for (int d = 0; d < DD / 4; ++d) {
            float4 w = wr[d];
            acc += w.x * x[4 * d] + w.y * x[4 * d + 1] + w.z * x[4 * d + 2] + w.w * x[4 * d + 3];
        }
        qh[tid] = acc;
    }
    __syncthreads();
#pragma unroll
    for (int k = 0; k < 2; ++k) {
        int d = tid + 256 * k;
        float acc = 0.f;
#pragma unroll 8
        for (int j = 0; j < HDD; ++j)
            acc += qh[j] * Wk[(size_t)(h * HDD + j) * DD + d];
        u[(size_t)(b * HH + h) * DD + d] = acc * SCALE_F;
    }
}

// ---------------- B: wt[b,h,t] = exp(u[b,h,:].enc[b,t,:]); lsum per chunk ----
// grid = B*64; 1 wave per t-row; R3-verified fold butterfly. No max (|s|<~3).
__global__ __launch_bounds__(256) void k_sexp(const float* __restrict__ enc,
                                              const float* __restrict__ u,
                                              float* __restrict__ wt,
                                              float* __restrict__ lsum) {
    __shared__ float stile[HH][66];
    int b = blockIdx.x >> 6;
    int c = blockIdx.x & 63;
    int t0 = c * 64;
    int wave = threadIdx.x >> 6, lane = threadIdx.x & 63;
    int tid = threadIdx.x;
    const float* ub = u + (size_t)b * HH * DD;
    float4 uA[HH], uB[HH];
#pragma unroll
    for (int h = 0; h < HH; ++h) {
        uA[h] = *(const float4*)(ub + h * DD + 4 * lane);
        uB[h] = *(const float4*)(ub + h * DD + 256 + 4 * lane);
    }
    bool b3 = (lane & 8) != 0, b4 = (lane & 16) != 0, b5 = (lane & 32) != 0;
    int myh = ((lane >> 3) & 1) * 4 + ((lane >> 4) & 1) * 2 + ((lane >> 5) & 1);
    for (int tt = wave; tt < 64; tt += 4) {
        int t = t0 + tt;
        const float* row = enc + ((size_t)b * TT + t) * DD;
        float4 e0 = *(const float4*)(row + 4 * lane);
        float4 e1 = *(const float4*)(row + 256 + 4 * lane);
        float a[HH];
#pragma unroll
        for (int h = 0; h < HH; ++h)
            a[h] = uA[h].x * e0.x + uA[h].y * e0.y + uA[h].z * e0.z + uA[h].w * e0.w
                 + uB[h].x * e1.x + uB[h].y * e1.y + uB[h].z * e1.z + uB[h].w * e1.w;
        float s[4];
#pragma unroll
        for (int j = 0; j < 4; ++j) {
            float snd = b3 ? a[j] : a[j + 4];
            float kp  = b3 ? a[j + 4] : a[j];
            s[j] = kp + __shfl_xor(snd, 8, 64);
        }
        float p[2];
#pragma unroll
        for (int j = 0; j < 2; ++j) {
            float snd = b4 ? s[j] : s[j + 2];
            float kp  = b4 ? s[j + 2] : s[j];
            p[j] = kp + __shfl_xor(snd, 16, 64);
        }
        float snd = b5 ? p[0] : p[1];
        float q0 = (b5 ? p[1] : p[0]) + __shfl_xor(snd, 32, 64);
        q0 += __shfl_xor(q0, 1, 64);
        q0 += __shfl_xor(q0, 2, 64);
        q0 += __shfl_xor(q0, 4, 64);
        if ((lane & 7) == 0) stile[myh][tt] = __expf(q0);
    }
    __syncthreads();
#pragma unroll
    for (int k = 0; k < 2; ++k) {
        int idx = tid + 256 * k;
        int h = idx >> 6, tt = idx & 63;
        wt[(size_t)(b * HH + h) * TT + t0 + tt] = stile[h][tt];
    }
    if (tid < HH) {
        float s = 0.f;
#pragma unroll
        for (int t = 0; t < 64; ++t) s += stile[tid][t];
        lsum[(size_t)(b * NCHS + c) * HH + tid] = s;
    }
}

// ---------------- E: partial[b,c,h,d] = sum_{t in chunk} wt[b,h,t]*enc[b,t,d] -
__global__ __launch_bounds__(256) void k_wsum(const float* __restrict__ enc,
                                              const float* __restrict__ wt,
                                              float* __restrict__ partial) {
    __shared__ float wl[HH * TC];   // 4 KiB [h][t]
    __shared__ float mrg[HH * DD];  // 16 KiB
    int b = blockIdx.x / CHUNKS, c = blockIdx.x % CHUNKS;
    int t0 = c * TC, tid = threadIdx.x;
    {
        int h = tid >> 5, i0 = (tid & 31) * 4;
        *(float4*)(wl + h * TC + i0) =
            *(const float4*)(wt + (size_t)(b * HH + h) * TT + t0 + i0);
    }
    __syncthreads();
    int grp = tid >> 7, gl = tid & 127;
    float4 acc[HH];
#pragma unroll
    for (int h = 0; h < HH; ++h) acc[h] = make_float4(0.f, 0.f, 0.f, 0.f);
#pragma unroll 4
    for (int i = 0; i < TC / 2; ++i) {
        int r = grp + 2 * i;
        float4 e = *(const float4*)(enc + ((size_t)b * TT + t0 + r) * DD + gl * 4);
        float w0 = wl[0 * TC + r], w1 = wl[1 * TC + r], w2 = wl[2 * TC + r], w3 = wl[3 * TC + r];
        float w4 = wl[4 * TC + r], w5 = wl[5 * TC + r], w6 = wl[6 * TC + r], w7 = wl[7 * TC + r];
        acc[0].x += w0 * e.x; acc[0].y += w0 * e.y; acc[0].z += w0 * e.z; acc[0].w += w0 * e.w;
        acc[1].x += w1 * e.x; acc[1].y += w1 * e.y; acc[1].z += w1 * e.z; acc[1].w += w1 * e.w;
        acc[2].x += w2 * e.x; acc[2].y += w2 * e.y; acc[2].z += w2 * e.z; acc[2].w += w2 * e.w;
        acc[3].x += w3 * e.x; acc[3].y += w3 * e.y; acc[3].z += w3 * e.z; acc[3].w += w3 * e.w;
        acc[4].x += w4 * e.x; acc[4].y += w4 * e.y; acc[4].z += w4 * e.z; acc[4].w += w4 * e.w;
        acc[5].x += w5 * e.x; acc[5].y += w5 * e.y; acc[5].z += w5 * e.z; acc[5].w += w5 * e.w;
        acc[6].x += w6 * e.x; acc[6].y += w6 * e.y; acc[6].z += w6 * e.z; acc[6].w += w6 * e.w;
        acc[7].x += w7 * e.x; acc[7].y += w7 * e.y; acc[7].z += w7 * e.z; acc[7].w += w7 * e.w;
    }
    if (grp == 1) {
#pragma unroll
        for (int h = 0; h < HH; ++h) *(float4*)(mrg + h * DD + gl * 4) = acc[h];
    }
    __syncthreads();
    if (grp == 0) {
        float* pp = partial + (size_t)(b * CHUNKS + c) * HH * DD + gl * 4;
#pragma unroll
        for (int h = 0; h < HH; ++h) {
            float4 m = *(const float4*)(mrg + h * DD + gl * 4);
            float4 r = acc[h];
            r.x += m.x; r.y += m.y; r.z += m.z; r.w += m.w;
            *(float4*)(pp + h * DD) = r;
        }
    }
}

// ---------------- F: ctx[b,h,d] = (sum_c partial) / L[b,h] -------------------
__global__ __launch_bounds__(256) void k_pred(const float* __restrict__ partial,
                                              const float* __restrict__ lsum,
                                              float* __restrict__ ctx) {
    int idx = blockIdx.x * 256 + threadIdx.x;   // over B*H*D/4
    int b = idx >> 10, r4 = (idx & 1023) * 4;
    int h = r4 >> 9;
    float L = 0.f;
#pragma unroll 8
    for (int c = 0; c < NCHS; ++c) L += lsum[(size_t)(b * NCHS + c) * HH + h];
    const float* pp = partial + (size_t)b * CHUNKS * HH * DD + r4;
    float4 acc = make_float4(0.f, 0.f, 0.f, 0.f);
#pragma unroll 8
    for (int c = 0; c < CHUNKS; ++c) {
        float4 v = *(const float4*)(pp + (size_t)c * HH * DD);
        acc.x += v.x; acc.y += v.y; acc.z += v.z; acc.w += v.w;
    }
    float inv = 1.0f / L;
    acc.x *= inv; acc.y *= inv; acc.z *= inv; acc.w *= inv;
    *(float4*)(ctx + (size_t)b * HH * DD + r4) = acc;
}

// ---------------- D: out1[b,t] = (1/8) sum_h wt[b,h,t] / L[b,h] --------------
__global__ __launch_bounds__(256) void k_out1(const float* __restrict__ wt,
                                              const float* __restrict__ lsum,
                                              float* __restrict__ out1) {
    __shared__ float Linv[HH];
    int b = blockIdx.x, tid = threadIdx.x;
    if (tid < HH) {
        float s = 0.f;
#pragma unroll 8
        for (int c = 0; c < NCHS; ++c) s += lsum[(size_t)(b * NCHS + c) * HH + tid];
        Linv[tid] = 0.125f / s;
    }
    __syncthreads();
#pragma unroll
    for (int k = 0; k < TT / 256; ++k) {
        int t = tid + 256 * k;
        float s = 0.f;
#pragma unroll
        for (int h = 0; h < HH; ++h)
            s += wt[(size_t)(b * HH + h) * TT + t] * Linv[h];
        out1[(size_t)b * TT + t] = s;
    }
}

// ---------------- G1: ctxv[b, h*64+o] = Wv[h*64+o, :] . ctx[b,h,:] -----------
// grid = B*H blocks; 4 lanes per output (quad reduce).
__global__ __launch_bounds__(256) void k_v(const float* __restrict__ ctx,
                                           const float* __restrict__ Wv,
                                           float* __restrict__ ctxv) {
    __shared__ float cs[DD];
    int b = blockIdx.x >> 3, h = blockIdx.x & 7;
    int tid = threadIdx.x;
    for (int i = tid; i < DD; i += 256) cs[i] = ctx[(size_t)b * HH * DD + h * DD + i];
    __syncthreads();
    int out = tid >> 2, q = tid & 3;
    int i = h * HDD + out;
    const float4* wr = (const float4*)(Wv + (size_t)i * DD + q * 128);
    const float* cc = cs + q * 128;
    float acc = 0.f;
#pragma unroll 8
    for (int d = 0; d < 32; ++d) {
        float4 w = wr[d];
        acc += w.x * cc[4 * d] + w.y * cc[4 * d + 1] + w.z * cc[4 * d + 2] + w.w * cc[4 * d + 3];
    }
    acc += __shfl_xor(acc, 1, 64);
    acc += __shfl_xor(acc, 2, 64);
    if (q == 0) ctxv[(size_t)b * DD + i] = acc;
}

// ---------------- G2: out0[b, g*64+o] = Wo[g*64+o, :] . ctxv[b,:] ------------
__global__ __launch_bounds__(256) void k_o(const float* __restrict__ ctxv,
                                           const float* __restrict__ Wo,
                                           float* __restrict__ out0) {
    __shared__ float cs[DD];
    int b = blockIdx.x >> 3, g = blockIdx.x & 7;
    int tid = threadIdx.x;
    for (int i = tid; i < DD; i += 256) cs[i] = ctxv[(size_t)b * DD + i];
    __syncthreads();
    int out = tid >> 2, q = tid & 3;
    int o = g * HDD + out;
    const float4* wr = (const float4*)(Wo + (size_t)o * DD + q * 128);
    const float* cc = cs + q * 128;
    float acc = 0.f;
#pragma unroll 8
    for (int d = 0; d < 32; ++d) {
        float4 w = wr[d];
        acc += w.x * cc[4 * d] + w.y * cc[4 * d + 1] + w.z * cc[4 * d + 2] + w.w * cc[4 * d + 3];
    }
    acc += __shfl_xor(acc, 1, 64);
    acc += __shfl_xor(acc, 2, 64);
    if (q == 0) out0[(size_t)b * DD + o] = acc;
}

extern "C" void kernel_launch(void* const* d_in, const int* in_sizes, int n_in,
                              void* d_out, int out_size, void* d_ws, size_t ws_size,
                              hipStream_t stream) {
    const float* enc = (const float*)d_in[0];
    const float* Wq  = (const float*)d_in[1];
    const float* Wk  = (const float*)d_in[2];
    const float* Wv  = (const float*)d_in[3];
    const float* Wo  = (const float*)d_in[4];

    float* ws = (float*)d_ws;
    float* u       = ws;                                      // B*H*D        = 131072
    float* wt      = u + (size_t)BB * HH * DD;                // B*H*T        = 1048576
    float* lsum    = wt + (size_t)BB * HH * TT;               // B*NCHS*H     = 16384
    float* partial = lsum + (size_t)BB * NCHS * HH;           // B*CHUNKS*H*D = 4194304
    float* ctx     = partial + (size_t)BB * CHUNKS * HH * DD; // B*H*D        = 131072
    float* ctxv    = ctx + (size_t)BB * HH * DD;              // B*D          = 16384
    // total ~5.5M floats (~22 MB)

    float* out0 = (float*)d_out;          // [B, D]
    float* out1 = out0 + BB * DD;         // [B, T]

    hipLaunchKernelGGL(k_qu,    dim3(BB * HH),     dim3(256), 0, stream, enc, Wq, Wk, u);
    hipLaunchKernelGGL(k_sexp,  dim3(BB * NCHS),   dim3(256), 0, stream, enc, u, wt, lsum);
    hipLaunchKernelGGL(k_wsum,  dim3(BB * CHUNKS), dim3(256), 0, stream, enc, wt, partial);
    hipLaunchKernelGGL(k_pred,  dim3(BB * HH * DD / 1024), dim3(256), 0, stream, partial, lsum, ctx);
    hipLaunchKernelGGL(k_v,     dim3(BB * HH),     dim3(256), 0, stream, ctx, Wv, ctxv);
    hipLaunchKernelGGL(k_o,     dim3(BB * HH),     dim3(256), 0, stream, ctxv, Wo, out0);
    hipLaunchKernelGGL(k_out1,  dim3(BB),          dim3(256), 0, stream, wt, lsum, out1);
}

// Round 6
// 416.489 us; speedup vs baseline: 1.3327x; 1.1893x over previous
//
#include <hip/hip_runtime.h>

#define BB 32
#define TT 4096
#define DD 512
#define HH 8
#define HDD 64
#define SCALE_F 0.125f   // 64^-0.5 exact
#define CHUNKS 32        // chunks per batch (128 rows each)
#define TC 128           // rows per chunk
#define TILE 32          // rows per LDS tile
#define NT (TC / TILE)   // 4 tiles per chunk

// ---------------- A: u[b,h,:] = SCALE * Wk_h^T (Wq_h . enc[b,-1,:]) ----------
__global__ __launch_bounds__(256) void k_qu(const float* __restrict__ enc,
                                            const float* __restrict__ Wq,
                                            const float* __restrict__ Wk,
                                            float* __restrict__ u) {
    __shared__ float x[DD];
    __shared__ float qh[HDD];
    int b = blockIdx.x >> 3, h = blockIdx.x & 7;
    int tid = threadIdx.x;
    const float* el = enc + ((size_t)b * TT + (TT - 1)) * DD;
    for (int i = tid; i < DD; i += 256) x[i] = el[i];
    __syncthreads();
    if (tid < HDD) {
        const float4* wr = (const float4*)(Wq + (size_t)(h * HDD + tid) * DD);
        float acc = 0.f;
#pragma unroll 4
        for (int d = 0; d < DD / 4; ++d) {
            float4 w = wr[d];
            acc += w.x * x[4 * d] + w.y * x[4 * d + 1] + w.z * x[4 * d + 2] + w.w * x[4 * d + 3];
        }
        qh[tid] = acc;
    }
    __syncthreads();
#pragma unroll
    for (int k = 0; k < 2; ++k) {
        int d = tid + 256 * k;
        float acc = 0.f;
#pragma unroll 8
        for (int j = 0; j < HDD; ++j)
            acc += qh[j] * Wk[(size_t)(h * HDD + j) * DD + d];
        u[(size_t)(b * HH + h) * DD + d] = acc * SCALE_F;
    }
}

// ---------------- B: fused scores+exp+wsum, single enc pass via LDS tile -----
// grid = B*CHUNKS. Per 32-row tile: stage->LDS, scores from LDS, wsum from LDS.
__global__ __launch_bounds__(256) void k_main(const float* __restrict__ enc,
                                              const float* __restrict__ u,
                                              float* __restrict__ wt,
                                              float* __restrict__ lsum,
                                              float* __restrict__ partial) {
    __shared__ float et[TILE * DD];      // 64 KiB enc tile
    __shared__ float stile[TILE][HH];    // 1 KiB, [t][h] so wsum reads 2x float4 bcast
    int b = blockIdx.x / CHUNKS, c = blockIdx.x % CHUNKS;
    int t0 = c * TC;
    int tid = threadIdx.x, wave = tid >> 6, lane = tid & 63;

    const float* ub = u + (size_t)b * HH * DD;
    float4 uA[HH], uB[HH];
#pragma unroll
    for (int h = 0; h < HH; ++h) {
        uA[h] = *(const float4*)(ub + h * DD + 4 * lane);
        uB[h] = *(const float4*)(ub + h * DD + 256 + 4 * lane);
    }
    bool b3 = (lane & 8) != 0, b4 = (lane & 16) != 0, b5 = (lane & 32) != 0;
    int myh = ((lane >> 3) & 1) * 4 + ((lane >> 4) & 1) * 2 + ((lane >> 5) & 1);

    float Lacc = 0.f;          // valid on tid<8
    float2 acc[HH];
#pragma unroll
    for (int h = 0; h < HH; ++h) acc[h] = make_float2(0.f, 0.f);
    int d0 = tid * 2;

    for (int tile = 0; tile < NT; ++tile) {
        int tb = t0 + tile * TILE;
        // ---- stage 32 rows (64 KiB): 16 float4 per thread, coalesced ----
        const float4* gp = (const float4*)(enc + (size_t)(b * TT + tb) * DD);
        float4* lp = (float4*)et;
#pragma unroll
        for (int k = 0; k < 16; ++k) {
            int idx = tid + 256 * k;
            lp[idx] = gp[idx];
        }
        __syncthreads();
        // ---- phase 1: scores + exp (R3/R5-verified fold butterfly) ----
        for (int tt = wave; tt < TILE; tt += 4) {
            const float* row = et + tt * DD;
            float4 e0 = *(const float4*)(row + 4 * lane);
            float4 e1 = *(const float4*)(row + 256 + 4 * lane);
            float a[HH];
#pragma unroll
            for (int h = 0; h < HH; ++h)
                a[h] = uA[h].x * e0.x + uA[h].y * e0.y + uA[h].z * e0.z + uA[h].w * e0.w
                     + uB[h].x * e1.x + uB[h].y * e1.y + uB[h].z * e1.z + uB[h].w * e1.w;
            float s[4];
#pragma unroll
            for (int j = 0; j < 4; ++j) {
                float snd = b3 ? a[j] : a[j + 4];
                float kp  = b3 ? a[j + 4] : a[j];
                s[j] = kp + __shfl_xor(snd, 8, 64);
            }
            float p[2];
#pragma unroll
            for (int j = 0; j < 2; ++j) {
                float snd = b4 ? s[j] : s[j + 2];
                float kp  = b4 ? s[j + 2] : s[j];
                p[j] = kp + __shfl_xor(snd, 16, 64);
            }
            float snd = b5 ? p[0] : p[1];
            float q0 = (b5 ? p[1] : p[0]) + __shfl_xor(snd, 32, 64);
            q0 += __shfl_xor(q0, 1, 64);
            q0 += __shfl_xor(q0, 2, 64);
            q0 += __shfl_xor(q0, 4, 64);
            if ((lane & 7) == 0) stile[tt][myh] = __expf(q0);
        }
        __syncthreads();
        // ---- emit wt tile; accumulate lsum on tid<8 ----
        {
            int h = tid >> 5, ttv = tid & 31;
            wt[(size_t)(b * HH + h) * TT + tb + ttv] = stile[ttv][h];
        }
        if (tid < HH) {
#pragma unroll
            for (int t = 0; t < TILE; ++t) Lacc += stile[t][tid];
        }
        // ---- phase 2: weighted sum from LDS (float2 per lane over D) ----
#pragma unroll 4
        for (int r = 0; r < TILE; ++r) {
            float2 e = *(const float2*)(et + r * DD + d0);
            const float4* sp = (const float4*)stile[r];   // broadcast reads
            float4 w0 = sp[0], w1 = sp[1];
            acc[0].x += w0.x * e.x; acc[0].y += w0.x * e.y;
            acc[1].x += w0.y * e.x; acc[1].y += w0.y * e.y;
            acc[2].x += w0.z * e.x; acc[2].y += w0.z * e.y;
            acc[3].x += w0.w * e.x; acc[3].y += w0.w * e.y;
            acc[4].x += w1.x * e.x; acc[4].y += w1.x * e.y;
            acc[5].x += w1.y * e.x; acc[5].y += w1.y * e.y;
            acc[6].x += w1.z * e.x; acc[6].y += w1.z * e.y;
            acc[7].x += w1.w * e.x; acc[7].y += w1.w * e.y;
        }
        __syncthreads();   // et reused next tile
    }
    float* pp = partial + (size_t)(b * CHUNKS + c) * HH * DD + d0;
#pragma unroll
    for (int h = 0; h < HH; ++h) *(float2*)(pp + h * DD) = acc[h];
    if (tid < HH) lsum[(size_t)(b * CHUNKS + c) * HH + tid] = Lacc;
}

// ---------------- C: ctx reduce + normalize + Wv dot  (grid B*H) -------------
__global__ __launch_bounds__(256) void k_vctx(const float* __restrict__ partial,
                                              const float* __restrict__ lsum,
                                              const float* __restrict__ Wv,
                                              float* __restrict__ ctxv) {
    __shared__ float cs[DD];
    __shared__ float Linv;
    int b = blockIdx.x >> 3, h = blockIdx.x & 7;
    int tid = threadIdx.x;
    if (tid == 0) {
        float L = 0.f;
#pragma unroll 8
        for (int c = 0; c < CHUNKS; ++c) L += lsum[(size_t)(b * CHUNKS + c) * HH + h];
        Linv = 1.0f / L;
    }
    float a0 = 0.f, a1 = 0.f;
    const float* pb = partial + (size_t)(b * CHUNKS) * HH * DD + (size_t)h * DD;
#pragma unroll 8
    for (int c = 0; c < CHUNKS; ++c) {
        const float* pp = pb + (size_t)c * HH * DD;
        a0 += pp[tid]; a1 += pp[tid + 256];
    }
    __syncthreads();
    cs[tid] = a0 * Linv; cs[tid + 256] = a1 * Linv;
    __syncthreads();
    int out = tid >> 2, q = tid & 3;
    int i = h * HDD + out;
    const float4* wr = (const float4*)(Wv + (size_t)i * DD + q * 128);
    const float* cc = cs + q * 128;
    float acc = 0.f;
#pragma unroll 8
    for (int d = 0; d < 32; ++d) {
        float4 w = wr[d];
        acc += w.x * cc[4 * d] + w.y * cc[4 * d + 1] + w.z * cc[4 * d + 2] + w.w * cc[4 * d + 3];
    }
    acc += __shfl_xor(acc, 1, 64);
    acc += __shfl_xor(acc, 2, 64);
    if (q == 0) ctxv[(size_t)b * DD + i] = acc;
}

// ---------------- G2: out0[b, g*64+o] = Wo[g*64+o, :] . ctxv[b,:] ------------
__global__ __launch_bounds__(256) void k_o(const float* __restrict__ ctxv,
                                           const float* __restrict__ Wo,
                                           float* __restrict__ out0) {
    __shared__ float cs[DD];
    int b = blockIdx.x >> 3, g = blockIdx.x & 7;
    int tid = threadIdx.x;
    for (int i = tid; i < DD; i += 256) cs[i] = ctxv[(size_t)b * DD + i];
    __syncthreads();
    int out = tid >> 2, q = tid & 3;
    int o = g * HDD + out;
    const float4* wr = (const float4*)(Wo + (size_t)o * DD + q * 128);
    const float* cc = cs + q * 128;
    float acc = 0.f;
#pragma unroll 8
    for (int d = 0; d < 32; ++d) {
        float4 w = wr[d];
        acc += w.x * cc[4 * d] + w.y * cc[4 * d + 1] + w.z * cc[4 * d + 2] + w.w * cc[4 * d + 3];
    }
    acc += __shfl_xor(acc, 1, 64);
    acc += __shfl_xor(acc, 2, 64);
    if (q == 0) out0[(size_t)b * DD + o] = acc;
}

// ---------------- D: out1[b,t] = (1/8) sum_h wt[b,h,t] / L[b,h] --------------
// grid = B*8; each block covers 512 t's.
__global__ __launch_bounds__(256) void k_out1(const float* __restrict__ wt,
                                              const float* __restrict__ lsum,
                                              float* __restrict__ out1) {
    __shared__ float Linv[HH];
    int b = blockIdx.x >> 3, seg = blockIdx.x & 7;
    int tid = threadIdx.x;
    if (tid < HH) {
        float s = 0.f;
#pragma unroll 8
        for (int c = 0; c < CHUNKS; ++c) s += lsum[(size_t)(b * CHUNKS + c) * HH + tid];
        Linv[tid] = 0.125f / s;
    }
    __syncthreads();
#pragma unroll
    for (int k = 0; k < 2; ++k) {
        int t = seg * 512 + tid + 256 * k;
        float s = 0.f;
#pragma unroll
        for (int h = 0; h < HH; ++h)
            s += wt[(size_t)(b * HH + h) * TT + t] * Linv[h];
        out1[(size_t)b * TT + t] = s;
    }
}

extern "C" void kernel_launch(void* const* d_in, const int* in_sizes, int n_in,
                              void* d_out, int out_size, void* d_ws, size_t ws_size,
                              hipStream_t stream) {
    const float* enc = (const float*)d_in[0];
    const float* Wq  = (const float*)d_in[1];
    const float* Wk  = (const float*)d_in[2];
    const float* Wv  = (const float*)d_in[3];
    const float* Wo  = (const float*)d_in[4];

    float* ws = (float*)d_ws;
    float* u       = ws;                                      // B*H*D        = 131072
    float* wt      = u + (size_t)BB * HH * DD;                // B*H*T        = 1048576
    float* lsum    = wt + (size_t)BB * HH * TT;               // B*CHUNKS*H   = 8192
    float* partial = lsum + (size_t)BB * CHUNKS * HH;         // B*CHUNKS*H*D = 4194304
    float* ctxv    = partial + (size_t)BB * CHUNKS * HH * DD; // B*D          = 16384
    // total ~5.4M floats (~21.5 MB)

    float* out0 = (float*)d_out;          // [B, D]
    float* out1 = out0 + BB * DD;         // [B, T]

    hipLaunchKernelGGL(k_qu,    dim3(BB * HH),     dim3(256), 0, stream, enc, Wq, Wk, u);
    hipLaunchKernelGGL(k_main,  dim3(BB * CHUNKS), dim3(256), 0, stream, enc, u, wt, lsum, partial);
    hipLaunchKernelGGL(k_vctx,  dim3(BB * HH),     dim3(256), 0, stream, partial, lsum, Wv, ctxv);
    hipLaunchKernelGGL(k_o,     dim3(BB * HH),     dim3(256), 0, stream, ctxv, Wo, out0);
    hipLaunchKernelGGL(k_out1,  dim3(BB * HH),     dim3(256), 0, stream, wt, lsum, out1);
}